// Round 5
// baseline (136.629 us; speedup 1.0000x reference)
//
#include <hip/hip_runtime.h>
#include <hip/hip_bf16.h>

#define MODELS 64
#define BATCH 64
#define IN_DIM 512
#define UNITS 512
#define NCOLS 2048
// Packed-A: per tensor [m][ks16][kg4][row64] granules of 8 bf16 (16 B)
#define GRAN_PER_TENSOR (MODELS * 16 * 4 * 64)  // 262144 granules = 4 MB/tensor

typedef __attribute__((ext_vector_type(8))) short short8;
typedef __attribute__((ext_vector_type(4))) float f32x4;

static __device__ __forceinline__ short f2bf(float f) {
    return __builtin_bit_cast(short, __float2bfloat16(f));
}
static __device__ __forceinline__ float sigmoidf_(float x) {
    return 1.0f / (1.0f + __expf(-x));
}
static __device__ __forceinline__ float tanhf_(float x) {
    float e = __expf(-2.0f * fabsf(x));
    float r = (1.0f - e) / (1.0f + e);
    return copysignf(r, x);
}

// Re-layout inputs & h_tm1 (f32) into bf16 MFMA-A-fragment order.
__global__ __launch_bounds__(256) void prepack_A_kernel(
    const float* __restrict__ x, const float* __restrict__ h,
    short8* __restrict__ P)
{
    const int t = blockIdx.x * 256 + threadIdx.x;   // [0, 2*262144)
    const int tensor = t >> 18;
    const int r = t & (GRAN_PER_TENSOR - 1);
    const int kg = r & 3;
    const int row = (r >> 2) & 63;
    const int ks = (r >> 8) & 15;
    const int m = r >> 12;
    const float* src = (tensor ? h : x) + ((size_t)(m * 64 + row) * 512 + ks * 32 + kg * 8);
    f32x4 a0 = *(const f32x4*)src;
    f32x4 a1 = *(const f32x4*)(src + 4);
    short8 v;
    v[0] = f2bf(a0[0]); v[1] = f2bf(a0[1]); v[2] = f2bf(a0[2]); v[3] = f2bf(a0[3]);
    v[4] = f2bf(a1[0]); v[5] = f2bf(a1[1]); v[6] = f2bf(a1[2]); v[7] = f2bf(a1[3]);
    P[(size_t)tensor * GRAN_PER_TENSOR + (size_t)((m * 16 + ks) * 4 + kg) * 64 + row] = v;
}

// 512 blocks (model x 64-unit tile) x 512 threads (8 waves), 2 blocks/CU.
// LDS: two 32KB weight stage buffers (f32 [32k][256c], XOR-swizzled); reused as z[64][256].
__global__ __launch_bounds__(512, 4) void lstm_main_kernel(
    const float* __restrict__ c_tm1,
    const float* __restrict__ kernel_,
    const float* __restrict__ rkernel,
    const float* __restrict__ bias,
    const short8* __restrict__ Pa,
    float* __restrict__ out)
{
    __shared__ float lds[16384];  // 64 KB

    const int bid = blockIdx.x;
    const int m = bid >> 3;
    const int u0 = (bid & 7) * 64;
    const int tid = threadIdx.x;
    const int wave = tid >> 6;
    const int lane = tid & 63;
    const int col16 = lane & 15;
    const int kq = lane >> 4;

    const float* wbase[2] = { kernel_ + (size_t)m * IN_DIM * NCOLS,
                              rkernel + (size_t)m * UNITS * NCOLS };
    const short8* pabase[2] = { Pa + (size_t)m * 4096,
                                Pa + GRAN_PER_TENSOR + (size_t)m * 4096 };

    f32x4 acc[4][2];
#pragma unroll
    for (int bt = 0; bt < 4; ++bt)
#pragma unroll
        for (int c = 0; c < 2; ++c) acc[bt][c] = (f32x4){0.f, 0.f, 0.f, 0.f};

    // ---- stage one 32-row K-step into LDS buffer. Source col pre-swizzled
    //      (involution: dword position ^= (row>>3)<<3), LDS dest linear. ----
    auto STAGE = [&](int step, int bufsel) {
        const float* wb = wbase[step >> 4];
        const int krow0 = (step & 15) * 32;
#pragma unroll
        for (int j = 0; j < 4; ++j) {
            const int k = j * 8 + wave;                 // rows {w, w+8, w+16, w+24}
            const float* src = wb + (size_t)(krow0 + k) * NCOLS
                             + kq * 512 + u0 + ((col16 ^ (j << 1)) * 4);
            float* dst = lds + bufsel * 8192 + k * 256; // wave-uniform; HW adds lane*16
            __builtin_amdgcn_global_load_lds(
                (const __attribute__((address_space(1))) void*)src,
                (__attribute__((address_space(3))) void*)dst, 16, 0, 0);
        }
    };
    auto LOADA = [&](int step, short8* af) {
        const short8* pb = pabase[step >> 4] + (size_t)((step & 15) * 4 + kq) * 64 + col16;
#pragma unroll
        for (int bt = 0; bt < 4; ++bt)
            asm volatile("global_load_dwordx4 %0, %1, off"
                         : "=v"(af[bt]) : "v"(pb + bt * 16) : "memory");
    };
    // swizzled B-column read base (row-XOR key is kq<<3, constant per thread)
    auto COMPUTE = [&](int bufsel, short8* af) {
        const float* lb = lds + bufsel * 8192;
#pragma unroll
        for (int c = 0; c < 2; ++c) {
            const int cb = (wave * 2 + c) * 16 + col16;
            const int cbs = cb ^ (kq << 3);
            short8 bfr;
#pragma unroll
            for (int i = 0; i < 8; ++i)
                bfr[i] = f2bf(lb[(kq * 8 + i) * 256 + cbs]);
#pragma unroll
            for (int bt = 0; bt < 4; ++bt)
                acc[bt][c] = __builtin_amdgcn_mfma_f32_16x16x32_bf16(
                    af[bt], bfr, acc[bt][c], 0, 0, 0);
        }
    };

    short8 afA[4], afB[4];
    // prologue: step 0 into buf0/afA
    STAGE(0, 0);
    LOADA(0, afA);

    for (int tp = 0; tp < 16; ++tp) {
        const int te = 2 * tp;
        // ---- even step te: buf0, afA; prefetch te+1 -> buf1, afB ----
        STAGE(te + 1, 1);
        LOADA(te + 1, afB);
        asm volatile("s_waitcnt vmcnt(8)"   // drain stage_te + A_te (issued a full step ago)
                     : "+v"(afA[0]), "+v"(afA[1]), "+v"(afA[2]), "+v"(afA[3]) :: "memory");
        asm volatile("s_barrier" ::: "memory");
        COMPUTE(0, afA);
        asm volatile("s_waitcnt lgkmcnt(0)" ::: "memory");
        asm volatile("s_barrier" ::: "memory");
        // ---- odd step te+1: buf1, afB; prefetch te+2 -> buf0, afA ----
        if (tp < 15) {
            STAGE(te + 2, 0);
            LOADA(te + 2, afA);
            asm volatile("s_waitcnt vmcnt(8)"
                         : "+v"(afB[0]), "+v"(afB[1]), "+v"(afB[2]), "+v"(afB[3]) :: "memory");
        } else {
            asm volatile("s_waitcnt vmcnt(0)"
                         : "+v"(afB[0]), "+v"(afB[1]), "+v"(afB[2]), "+v"(afB[3]) :: "memory");
        }
        asm volatile("s_barrier" ::: "memory");
        COMPUTE(1, afB);
        asm volatile("s_waitcnt lgkmcnt(0)" ::: "memory");
        asm volatile("s_barrier" ::: "memory");
    }

    // ---- z exchange through LDS (stage buffers are free now) ----
#pragma unroll
    for (int bt = 0; bt < 4; ++bt)
#pragma unroll
        for (int c = 0; c < 2; ++c)
#pragma unroll
            for (int r = 0; r < 4; ++r)
                lds[(size_t)(bt * 16 + kq * 4 + r) * 256 + (wave * 2 + c) * 16 + col16] =
                    acc[bt][c][r];
    __syncthreads();

    // ---- fused gate epilogue: thread -> (batch b, 8 units) ----
    const int b = tid >> 3;
    const int ug = (tid & 7) * 8;

    float zi[8], zf[8], zc[8], zo[8];
    *(f32x4*)&zi[0] = *(const f32x4*)&lds[b * 256 + 0 + ug];
    *(f32x4*)&zi[4] = *(const f32x4*)&lds[b * 256 + 0 + ug + 4];
    *(f32x4*)&zf[0] = *(const f32x4*)&lds[b * 256 + 64 + ug];
    *(f32x4*)&zf[4] = *(const f32x4*)&lds[b * 256 + 64 + ug + 4];
    *(f32x4*)&zc[0] = *(const f32x4*)&lds[b * 256 + 128 + ug];
    *(f32x4*)&zc[4] = *(const f32x4*)&lds[b * 256 + 128 + ug + 4];
    *(f32x4*)&zo[0] = *(const f32x4*)&lds[b * 256 + 192 + ug];
    *(f32x4*)&zo[4] = *(const f32x4*)&lds[b * 256 + 192 + ug + 4];

    const float* bb = bias + (size_t)m * NCOLS;
    float bi[8], bf_[8], bc[8], bo[8];
    *(f32x4*)&bi[0] = *(const f32x4*)&bb[0 * 512 + u0 + ug];
    *(f32x4*)&bi[4] = *(const f32x4*)&bb[0 * 512 + u0 + ug + 4];
    *(f32x4*)&bf_[0] = *(const f32x4*)&bb[1 * 512 + u0 + ug];
    *(f32x4*)&bf_[4] = *(const f32x4*)&bb[1 * 512 + u0 + ug + 4];
    *(f32x4*)&bc[0] = *(const f32x4*)&bb[2 * 512 + u0 + ug];
    *(f32x4*)&bc[4] = *(const f32x4*)&bb[2 * 512 + u0 + ug + 4];
    *(f32x4*)&bo[0] = *(const f32x4*)&bb[3 * 512 + u0 + ug];
    *(f32x4*)&bo[4] = *(const f32x4*)&bb[3 * 512 + u0 + ug + 4];

    const size_t cidx = (size_t)m * (BATCH * UNITS) + (size_t)b * UNITS + u0 + ug;
    float cp[8];
    *(f32x4*)&cp[0] = *(const f32x4*)&c_tm1[cidx];
    *(f32x4*)&cp[4] = *(const f32x4*)&c_tm1[cidx + 4];

    float hv[8], cv[8];
#pragma unroll
    for (int j = 0; j < 8; ++j) {
        const float ig = sigmoidf_(zi[j] + bi[j]);
        const float fg = sigmoidf_(zf[j] + bf_[j]);
        const float cand = tanhf_(zc[j] + bc[j]);
        const float og = sigmoidf_(zo[j] + bo[j]);
        const float c = fg * cp[j] + ig * cand;
        cv[j] = c;
        hv[j] = og * tanhf_(c);
    }

    float* hout0 = out;
    float* hout1 = out + (size_t)MODELS * BATCH * UNITS;
    float* cout = out + 2 * (size_t)MODELS * BATCH * UNITS;
    *(f32x4*)&hout0[cidx] = *(const f32x4*)&hv[0];
    *(f32x4*)&hout0[cidx + 4] = *(const f32x4*)&hv[4];
    *(f32x4*)&hout1[cidx] = *(const f32x4*)&hv[0];
    *(f32x4*)&hout1[cidx + 4] = *(const f32x4*)&hv[4];
    *(f32x4*)&cout[cidx] = *(const f32x4*)&cv[0];
    *(f32x4*)&cout[cidx + 4] = *(const f32x4*)&cv[4];
}

extern "C" void kernel_launch(void* const* d_in, const int* in_sizes, int n_in,
                              void* d_out, int out_size, void* d_ws, size_t ws_size,
                              hipStream_t stream) {
    const float* inputs = (const float*)d_in[0];
    const float* h_tm1 = (const float*)d_in[1];
    const float* c_tm1 = (const float*)d_in[2];
    const float* kernel_ = (const float*)d_in[3];
    const float* rkernel = (const float*)d_in[4];
    const float* bias = (const float*)d_in[5];
    float* out = (float*)d_out;

    short8* P = (short8*)d_ws;  // 8 MB of scratch
    hipLaunchKernelGGL(prepack_A_kernel, dim3(2 * GRAN_PER_TENSOR / 256), dim3(256),
                       0, stream, inputs, h_tm1, P);
    hipLaunchKernelGGL(lstm_main_kernel, dim3(MODELS * 8), dim3(512), 0, stream,
                       c_tm1, kernel_, rkernel, bias, P, out);
}